// Round 1
// baseline (17674.954 us; speedup 1.0000x reference)
//
#include <hip/hip_runtime.h>

#define H    512
#define DOBS 256
#define BATCH 32
#define SEQ  2048

// ---------------- transpose 512x512: Wt[k][n] = W[n][k] ----------------
__global__ __launch_bounds__(256) void transpose_k(const float* __restrict__ W,
                                                   float* __restrict__ Wt) {
  __shared__ float tile[32][33];
  int tx  = threadIdx.x & 31;
  int ty4 = (threadIdx.x >> 5) * 4;  // 8 groups x 4 rows
  int bx = blockIdx.x * 32;
  int by = blockIdx.y * 32;
#pragma unroll
  for (int i = 0; i < 4; ++i)
    tile[ty4 + i][tx] = W[(by + ty4 + i) * H + bx + tx];
  __syncthreads();
#pragma unroll
  for (int i = 0; i < 4; ++i)
    Wt[(bx + ty4 + i) * H + by + tx] = tile[tx][ty4 + i];
}

// ---------------- C[M][N] = A[M][K] @ B[N][K]^T + bias[N] ----------------
// BM=BN=64, BK=32, 256 threads, 4x4 micro-tile per thread.
__global__ __launch_bounds__(256) void gemm_bias_k(const float* __restrict__ A,
                                                   const float* __restrict__ B,
                                                   const float* __restrict__ bias,
                                                   float* __restrict__ C,
                                                   int M, int N, int K) {
  __shared__ float As[32][68];  // [k][m], stride 68 floats = 272 B (16B-aligned rows)
  __shared__ float Bs[32][68];  // [k][n]
  const int m0 = blockIdx.x * 64;
  const int n0 = blockIdx.y * 64;
  const int t  = threadIdx.x;
  const int tm = (t >> 4) * 4;   // 0..60
  const int tn = (t & 15) * 4;   // 0..60
  const int lrow = t >> 3;        // 0..31
  const int lcol = (t & 7) * 4;   // 0..28

  float acc[4][4] = {};

  for (int k0 = 0; k0 < K; k0 += 32) {
    float4 a0 = *(const float4*)&A[(size_t)(m0 + lrow)      * K + k0 + lcol];
    float4 a1 = *(const float4*)&A[(size_t)(m0 + lrow + 32) * K + k0 + lcol];
    float4 b0 = *(const float4*)&B[(size_t)(n0 + lrow)      * K + k0 + lcol];
    float4 b1 = *(const float4*)&B[(size_t)(n0 + lrow + 32) * K + k0 + lcol];
    __syncthreads();
    As[lcol + 0][lrow] = a0.x; As[lcol + 1][lrow] = a0.y;
    As[lcol + 2][lrow] = a0.z; As[lcol + 3][lrow] = a0.w;
    As[lcol + 0][lrow + 32] = a1.x; As[lcol + 1][lrow + 32] = a1.y;
    As[lcol + 2][lrow + 32] = a1.z; As[lcol + 3][lrow + 32] = a1.w;
    Bs[lcol + 0][lrow] = b0.x; Bs[lcol + 1][lrow] = b0.y;
    Bs[lcol + 2][lrow] = b0.z; Bs[lcol + 3][lrow] = b0.w;
    Bs[lcol + 0][lrow + 32] = b1.x; Bs[lcol + 1][lrow + 32] = b1.y;
    Bs[lcol + 2][lrow + 32] = b1.z; Bs[lcol + 3][lrow + 32] = b1.w;
    __syncthreads();
#pragma unroll
    for (int k = 0; k < 32; ++k) {
      float4 a = *(const float4*)&As[k][tm];
      float4 b = *(const float4*)&Bs[k][tn];
      acc[0][0] = fmaf(a.x, b.x, acc[0][0]);
      acc[0][1] = fmaf(a.x, b.y, acc[0][1]);
      acc[0][2] = fmaf(a.x, b.z, acc[0][2]);
      acc[0][3] = fmaf(a.x, b.w, acc[0][3]);
      acc[1][0] = fmaf(a.y, b.x, acc[1][0]);
      acc[1][1] = fmaf(a.y, b.y, acc[1][1]);
      acc[1][2] = fmaf(a.y, b.z, acc[1][2]);
      acc[1][3] = fmaf(a.y, b.w, acc[1][3]);
      acc[2][0] = fmaf(a.z, b.x, acc[2][0]);
      acc[2][1] = fmaf(a.z, b.y, acc[2][1]);
      acc[2][2] = fmaf(a.z, b.z, acc[2][2]);
      acc[2][3] = fmaf(a.z, b.w, acc[2][3]);
      acc[3][0] = fmaf(a.w, b.x, acc[3][0]);
      acc[3][1] = fmaf(a.w, b.y, acc[3][1]);
      acc[3][2] = fmaf(a.w, b.z, acc[3][2]);
      acc[3][3] = fmaf(a.w, b.w, acc[3][3]);
    }
  }

  float4 b4 = *(const float4*)&bias[n0 + tn];
#pragma unroll
  for (int i = 0; i < 4; ++i) {
    float4 c;
    c.x = acc[i][0] + b4.x;
    c.y = acc[i][1] + b4.y;
    c.z = acc[i][2] + b4.z;
    c.w = acc[i][3] + b4.w;
    *(float4*)&C[(size_t)(m0 + tm + i) * N + n0 + tn] = c;
  }
}

// ---------------- recurrence: one WG per batch chain ----------------
// hid[b][t][:] initially holds xp_t; overwritten in place with h_t.
// Wt is Whh transposed: Wt[k][n] = Whh_w[n][k].
__global__ __launch_bounds__(512) void rnn_rec_k(float* __restrict__ hid,
                                                 const float* __restrict__ Wt,
                                                 const float* __restrict__ bias) {
  __shared__ __align__(16) float hprev[H];
  const int b = blockIdx.x;
  const int n = threadIdx.x;
  const float bn = bias[n];
  float* hb = hid + (size_t)b * SEQ * H;
  hprev[n] = 0.0f;
  __syncthreads();
  const float* w = Wt + n;  // column n, stride H
  for (int t = 0; t < SEQ; ++t) {
    float acc = hb[t * H + n] + bn;
#pragma unroll 4
    for (int k = 0; k < H; k += 4) {
      float4 h4 = *(const float4*)&hprev[k];
      acc = fmaf(w[(k + 0) * H], h4.x, acc);
      acc = fmaf(w[(k + 1) * H], h4.y, acc);
      acc = fmaf(w[(k + 2) * H], h4.z, acc);
      acc = fmaf(w[(k + 3) * H], h4.w, acc);
    }
    float hv = fmaxf(acc, 0.0f);
    __syncthreads();          // all reads of hprev done
    hprev[n] = hv;
    hb[t * H + n] = hv;
    __syncthreads();          // hprev updated for next step
  }
}

// ---------------- in-place row softmax over 512 cols ----------------
__global__ __launch_bounds__(256) void softmax_k(float* __restrict__ Z) {
  __shared__ float smax[4];
  __shared__ float ssum[4];
  float* row = Z + (size_t)blockIdx.x * H;
  const int t = threadIdx.x;
  float2 v = *(float2*)&row[2 * t];
  float m = fmaxf(v.x, v.y);
#pragma unroll
  for (int o = 32; o > 0; o >>= 1) m = fmaxf(m, __shfl_xor(m, o, 64));
  const int wave = t >> 6, lane = t & 63;
  if (lane == 0) smax[wave] = m;
  __syncthreads();
  m = fmaxf(fmaxf(smax[0], smax[1]), fmaxf(smax[2], smax[3]));
  const float LOG2E = 1.44269504088896f;
  float ex = exp2f((v.x - m) * LOG2E);
  float ey = exp2f((v.y - m) * LOG2E);
  float s = ex + ey;
#pragma unroll
  for (int o = 32; o > 0; o >>= 1) s += __shfl_xor(s, o, 64);
  if (lane == 0) ssum[wave] = s;
  __syncthreads();
  float inv = 1.0f / (ssum[0] + ssum[1] + ssum[2] + ssum[3]);
  float2 r;
  r.x = ex * inv;
  r.y = ey * inv;
  *(float2*)&row[2 * t] = r;
}

extern "C" void kernel_launch(void* const* d_in, const int* in_sizes, int n_in,
                              void* d_out, int out_size, void* d_ws, size_t ws_size,
                              hipStream_t stream) {
  const float* x     = (const float*)d_in[0];
  const float* Whx_w = (const float*)d_in[1];
  const float* Whx_b = (const float*)d_in[2];
  const float* Whh_w = (const float*)d_in[3];
  const float* Whh_b = (const float*)d_in[4];
  const float* Woh_w = (const float*)d_in[5];
  const float* Woh_b = (const float*)d_in[6];

  float* y   = (float*)d_out;                          // output_arr [32][2048][512]
  float* hid = (float*)d_out + (size_t)BATCH * SEQ * H; // hidden_arr [32][2048][512]
  float* Wt  = (float*)d_ws;                           // 512*512*4 = 1 MB

  const int M = BATCH * SEQ;  // 65536

  // 0) transpose Whh for coalesced recurrence loads
  transpose_k<<<dim3(16, 16), 256, 0, stream>>>(Whh_w, Wt);
  // 1) xp = x @ Whx_w^T + b  -> stored into hidden region (overwritten by h_t later)
  gemm_bias_k<<<dim3(M / 64, H / 64), 256, 0, stream>>>(x, Whx_w, Whx_b, hid, M, H, DOBS);
  // 2) sequential recurrence, one WG per batch chain
  rnn_rec_k<<<BATCH, H, 0, stream>>>(hid, Wt, Whh_b);
  // 3) z = h @ Woh_w^T + b -> y region
  gemm_bias_k<<<dim3(M / 64, H / 64), 256, 0, stream>>>(hid, Woh_w, Woh_b, y, M, H, H);
  // 4) in-place softmax per row
  softmax_k<<<M, 256, 0, stream>>>(y);
}

// Round 2
// 14191.348 us; speedup vs baseline: 1.2455x; 1.2455x over previous
//
#include <hip/hip_runtime.h>

#define H    512
#define DOBS 256
#define BATCH 32
#define SEQ  2048
#define NSLICE 8   // WGs per chain
#define NS 64      // outputs per WG

// ---------------- transpose 512x512: Wt[k][n] = W[n][k] ----------------
__global__ __launch_bounds__(256) void transpose_k(const float* __restrict__ W,
                                                   float* __restrict__ Wt) {
  __shared__ float tile[32][33];
  int tx  = threadIdx.x & 31;
  int ty4 = (threadIdx.x >> 5) * 4;  // 8 groups x 4 rows
  int bx = blockIdx.x * 32;
  int by = blockIdx.y * 32;
#pragma unroll
  for (int i = 0; i < 4; ++i)
    tile[ty4 + i][tx] = W[(by + ty4 + i) * H + bx + tx];
  __syncthreads();
#pragma unroll
  for (int i = 0; i < 4; ++i)
    Wt[(bx + ty4 + i) * H + by + tx] = tile[tx][ty4 + i];
}

__global__ __launch_bounds__(256) void zero_cnt_k(int* __restrict__ cnt) {
  cnt[threadIdx.x] = 0;
}

// ---------------- C[M][N] = A[M][K] @ B[N][K]^T + bias[N] ----------------
__global__ __launch_bounds__(256) void gemm_bias_k(const float* __restrict__ A,
                                                   const float* __restrict__ B,
                                                   const float* __restrict__ bias,
                                                   float* __restrict__ C,
                                                   int M, int N, int K) {
  __shared__ float As[32][68];
  __shared__ float Bs[32][68];
  const int m0 = blockIdx.x * 64;
  const int n0 = blockIdx.y * 64;
  const int t  = threadIdx.x;
  const int tm = (t >> 4) * 4;
  const int tn = (t & 15) * 4;
  const int lrow = t >> 3;
  const int lcol = (t & 7) * 4;

  float acc[4][4] = {};

  for (int k0 = 0; k0 < K; k0 += 32) {
    float4 a0 = *(const float4*)&A[(size_t)(m0 + lrow)      * K + k0 + lcol];
    float4 a1 = *(const float4*)&A[(size_t)(m0 + lrow + 32) * K + k0 + lcol];
    float4 b0 = *(const float4*)&B[(size_t)(n0 + lrow)      * K + k0 + lcol];
    float4 b1 = *(const float4*)&B[(size_t)(n0 + lrow + 32) * K + k0 + lcol];
    __syncthreads();
    As[lcol + 0][lrow] = a0.x; As[lcol + 1][lrow] = a0.y;
    As[lcol + 2][lrow] = a0.z; As[lcol + 3][lrow] = a0.w;
    As[lcol + 0][lrow + 32] = a1.x; As[lcol + 1][lrow + 32] = a1.y;
    As[lcol + 2][lrow + 32] = a1.z; As[lcol + 3][lrow + 32] = a1.w;
    Bs[lcol + 0][lrow] = b0.x; Bs[lcol + 1][lrow] = b0.y;
    Bs[lcol + 2][lrow] = b0.z; Bs[lcol + 3][lrow] = b0.w;
    Bs[lcol + 0][lrow + 32] = b1.x; Bs[lcol + 1][lrow + 32] = b1.y;
    Bs[lcol + 2][lrow + 32] = b1.z; Bs[lcol + 3][lrow + 32] = b1.w;
    __syncthreads();
#pragma unroll
    for (int k = 0; k < 32; ++k) {
      float4 a = *(const float4*)&As[k][tm];
      float4 b = *(const float4*)&Bs[k][tn];
      acc[0][0] = fmaf(a.x, b.x, acc[0][0]);
      acc[0][1] = fmaf(a.x, b.y, acc[0][1]);
      acc[0][2] = fmaf(a.x, b.z, acc[0][2]);
      acc[0][3] = fmaf(a.x, b.w, acc[0][3]);
      acc[1][0] = fmaf(a.y, b.x, acc[1][0]);
      acc[1][1] = fmaf(a.y, b.y, acc[1][1]);
      acc[1][2] = fmaf(a.y, b.z, acc[1][2]);
      acc[1][3] = fmaf(a.y, b.w, acc[1][3]);
      acc[2][0] = fmaf(a.z, b.x, acc[2][0]);
      acc[2][1] = fmaf(a.z, b.y, acc[2][1]);
      acc[2][2] = fmaf(a.z, b.z, acc[2][2]);
      acc[2][3] = fmaf(a.z, b.w, acc[2][3]);
      acc[3][0] = fmaf(a.w, b.x, acc[3][0]);
      acc[3][1] = fmaf(a.w, b.y, acc[3][1]);
      acc[3][2] = fmaf(a.w, b.z, acc[3][2]);
      acc[3][3] = fmaf(a.w, b.w, acc[3][3]);
    }
  }

  float4 b4 = *(const float4*)&bias[n0 + tn];
#pragma unroll
  for (int i = 0; i < 4; ++i) {
    float4 c;
    c.x = acc[i][0] + b4.x;
    c.y = acc[i][1] + b4.y;
    c.z = acc[i][2] + b4.z;
    c.w = acc[i][3] + b4.w;
    *(float4*)&C[(size_t)(m0 + tm + i) * N + n0 + tn] = c;
  }
}

// ---------------- recurrence: 32 chains x 8 slices, weights in VGPRs -------
// Each WG: batch b, outputs n0..n0+63, weights Wt[k][n0+l] resident in regs.
// h published through hid (d_out) with agent-scope stores; per-(b,slice)
// monotonic counters in ws provide the step barrier.
__global__ __launch_bounds__(256, 1) void rnn_rec_k(float* __restrict__ hid,
                                                    const float* __restrict__ Wt,
                                                    const float* __restrict__ bias,
                                                    int* __restrict__ cnt) {
  const int b     = blockIdx.x & (BATCH - 1);
  const int slice = blockIdx.x >> 5;
  const int n0    = slice * NS;
  const int tid   = threadIdx.x;
  const int w     = tid >> 6;   // wave 0..3 -> k chunk of 128
  const int l     = tid & 63;   // lane -> output n0+l (for partials)

  __shared__ __align__(16) float sh_h[H];
  __shared__ float sh_part[4][64];

  float* hb = hid + (size_t)b * SEQ * H;
  int*   cb = cnt + b * NSLICE;

  // one-time weight preload: wreg[j] = Wt[w*128+j][n0+l]
  float wreg[128];
  {
    const float* wp = Wt + (size_t)(w * 128) * H + n0 + l;
#pragma unroll
    for (int j = 0; j < 128; ++j) wreg[j] = wp[(size_t)j * H];
  }
  const float bn = bias[n0 + l];  // used by wave 0 only

  for (int t = 0; t < SEQ; ++t) {
    float xp = 0.f;
    if (w == 0) {
      xp = hb[(size_t)t * H + n0 + l];  // prefetch xp_t (overlaps poll)
      if (t > 0) {
        bool ready = (l >= NSLICE);
        while (!ready)
          ready = (__hip_atomic_load(&cb[l], __ATOMIC_ACQUIRE,
                                     __HIP_MEMORY_SCOPE_AGENT) >= t);
      }
    }
    __syncthreads();  // wave0 confirmed all peers finished step t-1

    // stage h_{t-1} into LDS (full 512, from IF via agent loads)
    if (t > 0) {
      const float* hp = hb + (size_t)(t - 1) * H;
      sh_h[tid]       = __hip_atomic_load(hp + tid, __ATOMIC_RELAXED,
                                          __HIP_MEMORY_SCOPE_AGENT);
      sh_h[tid + 256] = __hip_atomic_load(hp + tid + 256, __ATOMIC_RELAXED,
                                          __HIP_MEMORY_SCOPE_AGENT);
    } else {
      sh_h[tid] = 0.f;
      sh_h[tid + 256] = 0.f;
    }
    __syncthreads();

    // partial dot over this wave's k-chunk (LDS broadcast reads)
    float partial = 0.f;
    const float4* sh4 = (const float4*)&sh_h[w * 128];
#pragma unroll
    for (int j4 = 0; j4 < 32; ++j4) {
      float4 hv = sh4[j4];
      partial = fmaf(wreg[4 * j4 + 0], hv.x, partial);
      partial = fmaf(wreg[4 * j4 + 1], hv.y, partial);
      partial = fmaf(wreg[4 * j4 + 2], hv.z, partial);
      partial = fmaf(wreg[4 * j4 + 3], hv.w, partial);
    }
    sh_part[w][l] = partial;
    __syncthreads();

    if (w == 0) {
      float v = sh_part[0][l] + sh_part[1][l] + sh_part[2][l] + sh_part[3][l]
              + xp + bn;
      float hv = fmaxf(v, 0.f);
      __hip_atomic_store(&hb[(size_t)t * H + n0 + l], hv, __ATOMIC_RELAXED,
                         __HIP_MEMORY_SCOPE_AGENT);
      __threadfence();              // drain h stores to coherent point
      if (l == 0) atomicAdd(&cb[slice], 1);  // publish step t
    }
  }
}

// ---------------- in-place row softmax over 512 cols ----------------
__global__ __launch_bounds__(256) void softmax_k(float* __restrict__ Z) {
  __shared__ float smax[4];
  __shared__ float ssum[4];
  float* row = Z + (size_t)blockIdx.x * H;
  const int t = threadIdx.x;
  float2 v = *(float2*)&row[2 * t];
  float m = fmaxf(v.x, v.y);
#pragma unroll
  for (int o = 32; o > 0; o >>= 1) m = fmaxf(m, __shfl_xor(m, o, 64));
  const int wave = t >> 6, lane = t & 63;
  if (lane == 0) smax[wave] = m;
  __syncthreads();
  m = fmaxf(fmaxf(smax[0], smax[1]), fmaxf(smax[2], smax[3]));
  const float LOG2E = 1.44269504088896f;
  float ex = exp2f((v.x - m) * LOG2E);
  float ey = exp2f((v.y - m) * LOG2E);
  float s = ex + ey;
#pragma unroll
  for (int o = 32; o > 0; o >>= 1) s += __shfl_xor(s, o, 64);
  if (lane == 0) ssum[wave] = s;
  __syncthreads();
  float inv = 1.0f / (ssum[0] + ssum[1] + ssum[2] + ssum[3]);
  float2 r;
  r.x = ex * inv;
  r.y = ey * inv;
  *(float2*)&row[2 * t] = r;
}

extern "C" void kernel_launch(void* const* d_in, const int* in_sizes, int n_in,
                              void* d_out, int out_size, void* d_ws, size_t ws_size,
                              hipStream_t stream) {
  const float* x     = (const float*)d_in[0];
  const float* Whx_w = (const float*)d_in[1];
  const float* Whx_b = (const float*)d_in[2];
  const float* Whh_w = (const float*)d_in[3];
  const float* Whh_b = (const float*)d_in[4];
  const float* Woh_w = (const float*)d_in[5];
  const float* Woh_b = (const float*)d_in[6];

  float* y   = (float*)d_out;                           // output_arr [32][2048][512]
  float* hid = (float*)d_out + (size_t)BATCH * SEQ * H; // hidden_arr [32][2048][512]
  float* Wt  = (float*)d_ws;                            // 1 MB
  int*   cnt = (int*)((char*)d_ws + (1 << 20));         // 256 ints

  const int M = BATCH * SEQ;  // 65536

  transpose_k<<<dim3(16, 16), 256, 0, stream>>>(Whh_w, Wt);
  zero_cnt_k<<<1, BATCH * NSLICE, 0, stream>>>(cnt);
  gemm_bias_k<<<dim3(M / 64, H / 64), 256, 0, stream>>>(x, Whx_w, Whx_b, hid, M, H, DOBS);
  rnn_rec_k<<<BATCH * NSLICE, 256, 0, stream>>>(hid, Wt, Whh_b, cnt);
  gemm_bias_k<<<dim3(M / 64, H / 64), 256, 0, stream>>>(hid, Woh_w, Woh_b, y, M, H, H);
  softmax_k<<<M, 256, 0, stream>>>(y);
}

// Round 3
// 4389.791 us; speedup vs baseline: 4.0264x; 3.2328x over previous
//
#include <hip/hip_runtime.h>

#define H    512
#define DOBS 256
#define BATCH 32
#define SEQ  2048
#define NSLICE 8   // WGs per chain
#define NS 64      // outputs per WG

typedef float f8 __attribute__((ext_vector_type(8)));

// ---------------- transpose 512x512: Wt[k][n] = W[n][k] ----------------
__global__ __launch_bounds__(256) void transpose_k(const float* __restrict__ W,
                                                   float* __restrict__ Wt) {
  __shared__ float tile[32][33];
  int tx  = threadIdx.x & 31;
  int ty4 = (threadIdx.x >> 5) * 4;
  int bx = blockIdx.x * 32;
  int by = blockIdx.y * 32;
#pragma unroll
  for (int i = 0; i < 4; ++i)
    tile[ty4 + i][tx] = W[(by + ty4 + i) * H + bx + tx];
  __syncthreads();
#pragma unroll
  for (int i = 0; i < 4; ++i)
    Wt[(bx + ty4 + i) * H + by + tx] = tile[tx][ty4 + i];
}

// ---------------- C[M][N] = A[M][K] @ B[N][K]^T + bias[N] ----------------
__global__ __launch_bounds__(256) void gemm_bias_k(const float* __restrict__ A,
                                                   const float* __restrict__ B,
                                                   const float* __restrict__ bias,
                                                   float* __restrict__ C,
                                                   int M, int N, int K) {
  __shared__ float As[32][68];
  __shared__ float Bs[32][68];
  const int m0 = blockIdx.x * 64;
  const int n0 = blockIdx.y * 64;
  const int t  = threadIdx.x;
  const int tm = (t >> 4) * 4;
  const int tn = (t & 15) * 4;
  const int lrow = t >> 3;
  const int lcol = (t & 7) * 4;

  float acc[4][4] = {};

  for (int k0 = 0; k0 < K; k0 += 32) {
    float4 a0 = *(const float4*)&A[(size_t)(m0 + lrow)      * K + k0 + lcol];
    float4 a1 = *(const float4*)&A[(size_t)(m0 + lrow + 32) * K + k0 + lcol];
    float4 b0 = *(const float4*)&B[(size_t)(n0 + lrow)      * K + k0 + lcol];
    float4 b1 = *(const float4*)&B[(size_t)(n0 + lrow + 32) * K + k0 + lcol];
    __syncthreads();
    As[lcol + 0][lrow] = a0.x; As[lcol + 1][lrow] = a0.y;
    As[lcol + 2][lrow] = a0.z; As[lcol + 3][lrow] = a0.w;
    As[lcol + 0][lrow + 32] = a1.x; As[lcol + 1][lrow + 32] = a1.y;
    As[lcol + 2][lrow + 32] = a1.z; As[lcol + 3][lrow + 32] = a1.w;
    Bs[lcol + 0][lrow] = b0.x; Bs[lcol + 1][lrow] = b0.y;
    Bs[lcol + 2][lrow] = b0.z; Bs[lcol + 3][lrow] = b0.w;
    Bs[lcol + 0][lrow + 32] = b1.x; Bs[lcol + 1][lrow + 32] = b1.y;
    Bs[lcol + 2][lrow + 32] = b1.z; Bs[lcol + 3][lrow + 32] = b1.w;
    __syncthreads();
#pragma unroll
    for (int k = 0; k < 32; ++k) {
      float4 a = *(const float4*)&As[k][tm];
      float4 b = *(const float4*)&Bs[k][tn];
      acc[0][0] = fmaf(a.x, b.x, acc[0][0]);
      acc[0][1] = fmaf(a.x, b.y, acc[0][1]);
      acc[0][2] = fmaf(a.x, b.z, acc[0][2]);
      acc[0][3] = fmaf(a.x, b.w, acc[0][3]);
      acc[1][0] = fmaf(a.y, b.x, acc[1][0]);
      acc[1][1] = fmaf(a.y, b.y, acc[1][1]);
      acc[1][2] = fmaf(a.y, b.z, acc[1][2]);
      acc[1][3] = fmaf(a.y, b.w, acc[1][3]);
      acc[2][0] = fmaf(a.z, b.x, acc[2][0]);
      acc[2][1] = fmaf(a.z, b.y, acc[2][1]);
      acc[2][2] = fmaf(a.z, b.z, acc[2][2]);
      acc[2][3] = fmaf(a.z, b.w, acc[2][3]);
      acc[3][0] = fmaf(a.w, b.x, acc[3][0]);
      acc[3][1] = fmaf(a.w, b.y, acc[3][1]);
      acc[3][2] = fmaf(a.w, b.z, acc[3][2]);
      acc[3][3] = fmaf(a.w, b.w, acc[3][3]);
    }
  }

  float4 b4 = *(const float4*)&bias[n0 + tn];
#pragma unroll
  for (int i = 0; i < 4; ++i) {
    float4 c;
    c.x = acc[i][0] + b4.x;
    c.y = acc[i][1] + b4.y;
    c.z = acc[i][2] + b4.z;
    c.w = acc[i][3] + b4.w;
    *(float4*)&C[(size_t)(m0 + tm + i) * N + n0 + tn] = c;
  }
}

// ---------------- recurrence: 32 chains x 8 slices ------------------------
// Weights in VGPRs (ext_vector -> cannot spill). Communication: owners store
// h+1 into exch (y region of d_out); readers poll values directly (>=1.0 ==
// ready). 0xAA poison (-3e-13) and memset-0 both read not-ready. Clean h goes
// to hid (plain store, consumed by the later GEMM dispatch).
__global__ __launch_bounds__(256, 1) void rnn_rec_k(float* __restrict__ hid,
                                                    float* __restrict__ exch,
                                                    const float* __restrict__ Wt,
                                                    const float* __restrict__ bias) {
  const int b     = blockIdx.x & (BATCH - 1);
  const int slice = blockIdx.x >> 5;
  const int n0    = slice * NS;
  const int tid   = threadIdx.x;
  const int w     = tid >> 6;   // wave 0..3 -> k chunk of 128
  const int l     = tid & 63;

  __shared__ __align__(16) float shh[H];
  __shared__ float sh_part[2][4][NS];

  float* hb = hid  + (size_t)b * SEQ * H;
  float* eb = exch + (size_t)b * SEQ * H;

  // one-time weight preload into SSA vectors: Wv[i][j] = Wt[w*128+8i+j][n0+l]
  f8 Wv[16];
  {
    const float* wp = Wt + (size_t)(w * 128) * H + n0 + l;
#pragma unroll
    for (int i = 0; i < 16; ++i) {
#pragma unroll
      for (int j = 0; j < 8; ++j)
        Wv[i][j] = wp[(size_t)(i * 8 + j) * H];
    }
  }
  const float bn = bias[n0 + l];

  const float4* sh4 = (const float4*)&shh[w * 128];

  for (int t = 0; t < SEQ; ++t) {
    float xp = 0.f;
    if (w == 0) xp = hb[(size_t)t * H + n0 + l];  // prefetch xp_t

    float partial = 0.f;
    if (t > 0) {
      // poll this wave's 128-wide k-chunk of (h_{t-1}+1)
      const float* ep = eb + (size_t)(t - 1) * H + w * 128;
      float v0, v1;
      for (;;) {
        v0 = __hip_atomic_load(ep + l,      __ATOMIC_RELAXED, __HIP_MEMORY_SCOPE_AGENT);
        v1 = __hip_atomic_load(ep + 64 + l, __ATOMIC_RELAXED, __HIP_MEMORY_SCOPE_AGENT);
        if (!__any(!(v0 >= 1.0f && v1 >= 1.0f))) break;
      }
      // wave-local LDS broadcast (same wave produces & consumes its region)
      shh[w * 128 + l]      = v0 - 1.0f;
      shh[w * 128 + 64 + l] = v1 - 1.0f;
      asm volatile("s_waitcnt lgkmcnt(0)" ::: "memory");

      float a0 = 0.f, a1 = 0.f, a2 = 0.f, a3 = 0.f;
#pragma unroll
      for (int i = 0; i < 16; ++i) {
        float4 hA = sh4[2 * i];
        float4 hB = sh4[2 * i + 1];
        a0 = fmaf(Wv[i][0], hA.x, a0);
        a1 = fmaf(Wv[i][1], hA.y, a1);
        a2 = fmaf(Wv[i][2], hA.z, a2);
        a3 = fmaf(Wv[i][3], hA.w, a3);
        a0 = fmaf(Wv[i][4], hB.x, a0);
        a1 = fmaf(Wv[i][5], hB.y, a1);
        a2 = fmaf(Wv[i][6], hB.z, a2);
        a3 = fmaf(Wv[i][7], hB.w, a3);
      }
      partial = (a0 + a1) + (a2 + a3);
    }

    sh_part[t & 1][w][l] = partial;
    __syncthreads();  // one barrier per step; parity protects reuse

    if (w == 0) {
      float v = sh_part[t & 1][0][l] + sh_part[t & 1][1][l]
              + sh_part[t & 1][2][l] + sh_part[t & 1][3][l] + xp + bn;
      float hv = fmaxf(v, 0.f);
      // publish h+1 (self-flagging) for peers
      __hip_atomic_store(&eb[(size_t)t * H + n0 + l], hv + 1.0f,
                         __ATOMIC_RELAXED, __HIP_MEMORY_SCOPE_AGENT);
      // clean h for the output / next GEMM
      hb[(size_t)t * H + n0 + l] = hv;
    }
  }
}

// ---------------- in-place row softmax over 512 cols ----------------
__global__ __launch_bounds__(256) void softmax_k(float* __restrict__ Z) {
  __shared__ float smax[4];
  __shared__ float ssum[4];
  float* row = Z + (size_t)blockIdx.x * H;
  const int t = threadIdx.x;
  float2 v = *(float2*)&row[2 * t];
  float m = fmaxf(v.x, v.y);
#pragma unroll
  for (int o = 32; o > 0; o >>= 1) m = fmaxf(m, __shfl_xor(m, o, 64));
  const int wave = t >> 6, lane = t & 63;
  if (lane == 0) smax[wave] = m;
  __syncthreads();
  m = fmaxf(fmaxf(smax[0], smax[1]), fmaxf(smax[2], smax[3]));
  const float LOG2E = 1.44269504088896f;
  float ex = exp2f((v.x - m) * LOG2E);
  float ey = exp2f((v.y - m) * LOG2E);
  float s = ex + ey;
#pragma unroll
  for (int o = 32; o > 0; o >>= 1) s += __shfl_xor(s, o, 64);
  if (lane == 0) ssum[wave] = s;
  __syncthreads();
  float inv = 1.0f / (ssum[0] + ssum[1] + ssum[2] + ssum[3]);
  float2 r;
  r.x = ex * inv;
  r.y = ey * inv;
  *(float2*)&row[2 * t] = r;
}

extern "C" void kernel_launch(void* const* d_in, const int* in_sizes, int n_in,
                              void* d_out, int out_size, void* d_ws, size_t ws_size,
                              hipStream_t stream) {
  const float* x     = (const float*)d_in[0];
  const float* Whx_w = (const float*)d_in[1];
  const float* Whx_b = (const float*)d_in[2];
  const float* Whh_w = (const float*)d_in[3];
  const float* Whh_b = (const float*)d_in[4];
  const float* Woh_w = (const float*)d_in[5];
  const float* Woh_b = (const float*)d_in[6];

  float* y   = (float*)d_out;                           // output_arr; doubles as h+1 exchange
  float* hid = (float*)d_out + (size_t)BATCH * SEQ * H; // hidden_arr: xp then h
  float* Wt  = (float*)d_ws;                            // 1 MB

  const int M = BATCH * SEQ;  // 65536

  transpose_k<<<dim3(16, 16), 256, 0, stream>>>(Whh_w, Wt);
  gemm_bias_k<<<dim3(M / 64, H / 64), 256, 0, stream>>>(x, Whx_w, Whx_b, hid, M, H, DOBS);
  rnn_rec_k<<<BATCH * NSLICE, 256, 0, stream>>>(hid, y, Wt, Whh_b);
  gemm_bias_k<<<dim3(M / 64, H / 64), 256, 0, stream>>>(hid, Woh_w, Woh_b, y, M, H, H);
  softmax_k<<<M, 256, 0, stream>>>(y);
}